// Round 2
// 611.102 us; speedup vs baseline: 1.0401x; 1.0401x over previous
//
#include <hip/hip_runtime.h>

// ---------------------------------------------------------------------------
// EdgeFeatures (fp32 in / fp32 out):
//   out[i] = (e[i] @ Us_w^T + Us_b) + Vx[src[i]] + Vx[dst[i]]
//   Vx     = x @ Vs_w^T + Vs_b
// H=256, V=10000, E=300000.
// Memory-bound: e(307MB) + out(307MB) fp32 => ~98us HBM floor.
// GEMM: m97 recipe (128x128 tile, BK=32, 4 waves 2x2, 16x16x32 bf16 MFMA),
// A-tile fp32 register-staged + cvt->bf16 + ds_write; B-tile pre-converted
// to bf16 in ws and staged via global_load_lds width-16. fp32 accumulate.
// Epilogue: per-wave LDS transpose of the MFMA C-fragments so gathers are
// bf16x4 (8B) and stores are dwordx4 (16B) coalesced — the previous scalar
// epilogue (192 scalar VMEM/thread) was the latency bottleneck.
// ws layout: [0,128K) Us_w bf16 | [128K,256K) Vs_w bf16 | [256K,+5.12M) Vx bf16
// ---------------------------------------------------------------------------

typedef __bf16 bf16_t;
typedef __bf16 bf16x4 __attribute__((ext_vector_type(4)));
typedef __bf16 bf16x8 __attribute__((ext_vector_type(8)));
typedef float f32x4 __attribute__((ext_vector_type(4)));
typedef float f32x8 __attribute__((ext_vector_type(8)));

#define HDIM 256
#define NV 10000
#define NE 300000

__device__ __forceinline__ void async16(const bf16_t* g, bf16_t* l) {
  __builtin_amdgcn_global_load_lds(
      (const __attribute__((address_space(1))) void*)g,
      (__attribute__((address_space(3))) void*)l, 16, 0, 0);
}

// fp32 -> bf16 convert of both 256x256 weight matrices (65536 elems each)
__global__ __launch_bounds__(256) void cvt_weights(
    const float* __restrict__ us, const float* __restrict__ vs,
    bf16_t* __restrict__ us_o, bf16_t* __restrict__ vs_o) {
  const int i = (blockIdx.x * 256 + threadIdx.x) * 4;  // 64 blocks cover 65536
  f32x4 a = *(const f32x4*)(us + i);
  f32x4 b = *(const f32x4*)(vs + i);
  *(bf16x4*)(us_o + i) = __builtin_convertvector(a, bf16x4);
  *(bf16x4*)(vs_o + i) = __builtin_convertvector(b, bf16x4);
}

template <bool FUSED>
__global__ __launch_bounds__(256) void gemm(
    const float* __restrict__ A,      // M x 256 fp32 (e or x)
    const bf16_t* __restrict__ Wb,    // 256 x 256 bf16 row-major [n][k]
    const float* __restrict__ bias,   // 256 fp32
    const int* __restrict__ sIdxG,    // FUSED: src indices (E)
    const int* __restrict__ dIdxG,    // FUSED: dst indices (E)
    const bf16_t* __restrict__ Vx,    // FUSED: V x 256 bf16
    float* __restrict__ outF,         // FUSED: M x 256 fp32
    bf16_t* __restrict__ outB,        // !FUSED: M x 256 bf16 (Vx scratch)
    int M) {
  // union: K-loop [0,8K) As bf16 [128][32] | [8K,16K) Bs bf16 [128][32]
  //        epilogue: 4 per-wave [16][68] f32 staging regions (4352 B each)
  __shared__ __align__(16) char smem[4 * 16 * 68 * 4];  // 17408 B
  bf16_t* As = (bf16_t*)smem;
  bf16_t* Bs = (bf16_t*)(smem + 8192);
  __shared__ int sIdx[128];
  __shared__ int dIdx[128];

  const int tid = threadIdx.x;  // 0..255
  const int lane = tid & 63;
  const int wave = tid >> 6;
  const int wm = wave >> 1;  // wave row (0..1)
  const int wn = wave & 1;   // wave col (0..1)
  const int l15 = lane & 15;
  const int quad = lane >> 4;  // 0..3

  const int row0 = blockIdx.x * 128;
  const int n0 = blockIdx.y * 128;

  if (FUSED) {
    if (tid < 128) {
      int r = row0 + tid;
      if (r >= M) r = M - 1;
      sIdx[tid] = sIdxG[r];
    } else {
      int r = row0 + tid - 128;
      if (r >= M) r = M - 1;
      dIdx[tid - 128] = dIdxG[r];
    }
  }

  // --- A staging (fp32 -> regs -> cvt -> bf16 LDS) -------------------------
  // thread covers (row = tid>>1, khalf = tid&1): 16 consecutive floats / iter
  const int arow = tid >> 1;
  const int acol = (tid & 1) * 16;
  int garow = row0 + arow;
  if (garow >= M) garow = M - 1;
  const float* gA = A + (size_t)garow * HDIM + acol;
  bf16_t* lA = As + arow * 32 + acol;

  // --- B staging (bf16 async, m97 chunk map): chunk c=(tid | tid+256) ------
  // c -> row = c>>2 (of 128), kcol = (c&3)*8
  const bf16_t* gB0 = Wb + (size_t)(n0 + (tid >> 2)) * HDIM + (tid & 3) * 8;
  const bf16_t* gB1 = Wb + (size_t)(n0 + 64 + (tid >> 2)) * HDIM + (tid & 3) * 8;
  bf16_t* lB0 = Bs + tid * 8;
  bf16_t* lB1 = Bs + 2048 + tid * 8;

  f32x4 acc[4][4];
#pragma unroll
  for (int mi = 0; mi < 4; ++mi)
#pragma unroll
    for (int ni = 0; ni < 4; ++ni) {
      f32x4 z = {0.f, 0.f, 0.f, 0.f};
      acc[mi][ni] = z;
    }

  // fragment LDS offsets: A[m = wm*64+mi*16+l15][k = quad*8 + j]
  const int aBase = (wm * 64 + l15) * 32 + quad * 8;
  const int bBase = (wn * 64 + l15) * 32 + quad * 8;

  // prefetch first A chunk
  f32x4 pa0 = *(const f32x4*)(gA + 0);
  f32x4 pa1 = *(const f32x4*)(gA + 4);
  f32x4 pa2 = *(const f32x4*)(gA + 8);
  f32x4 pa3 = *(const f32x4*)(gA + 12);

  for (int k0 = 0; k0 < HDIM; k0 += 32) {
    // B: async global->LDS (fire and forget; drained by barrier)
    async16(gB0 + k0, lB0);
    async16(gB1 + k0, lB1);

    // A: consume prefetched regs, start next prefetch
    f32x4 c0 = pa0, c1 = pa1, c2 = pa2, c3 = pa3;
    if (k0 + 32 < HDIM) {
      pa0 = *(const f32x4*)(gA + k0 + 32);
      pa1 = *(const f32x4*)(gA + k0 + 36);
      pa2 = *(const f32x4*)(gA + k0 + 40);
      pa3 = *(const f32x4*)(gA + k0 + 44);
    }
    f32x8 lo = {c0[0], c0[1], c0[2], c0[3], c1[0], c1[1], c1[2], c1[3]};
    f32x8 hi = {c2[0], c2[1], c2[2], c2[3], c3[0], c3[1], c3[2], c3[3]};
    *(bf16x8*)(lA + 0) = __builtin_convertvector(lo, bf16x8);
    *(bf16x8*)(lA + 8) = __builtin_convertvector(hi, bf16x8);

    __syncthreads();  // drains vmcnt (async B) + lgkmcnt (A writes)

    bf16x8 af[4], bfr[4];
#pragma unroll
    for (int mi = 0; mi < 4; ++mi)
      af[mi] = *(const bf16x8*)(As + aBase + mi * 16 * 32);
#pragma unroll
    for (int ni = 0; ni < 4; ++ni)
      bfr[ni] = *(const bf16x8*)(Bs + bBase + ni * 16 * 32);
#pragma unroll
    for (int mi = 0; mi < 4; ++mi)
#pragma unroll
      for (int ni = 0; ni < 4; ++ni)
        acc[mi][ni] = __builtin_amdgcn_mfma_f32_16x16x32_bf16(
            af[mi], bfr[ni], acc[mi][ni], 0, 0, 0);
    __syncthreads();  // protect LDS before next overwrite
  }
  // After the final barrier all waves' LDS reads are done -> As/Bs space is
  // reusable as per-wave epilogue staging (no cross-wave sharing below).

  // --- epilogue: C/D layout col = lane&15, row = quad*4 + reg ---------------
  // Stage acc(+bias) into per-wave [16][68] f32 LDS, then re-read coalesced:
  //   read lane map: row = lane>>2 (16 rows), 4-col chunk = (lane&3)*4 + i*16
  // -> gathers become bf16x4 (32B/4-lane group), stores dwordx4 (64B/group).
  // DS ops are in-order within a wave; staging is wave-private => no barrier.
  float bcol[4];
#pragma unroll
  for (int ni = 0; ni < 4; ++ni)
    bcol[ni] = bias[n0 + wn * 64 + ni * 16 + l15];

  float* stage = (float*)smem + wave * (16 * 68);
  const int srow = lane >> 2;       // 0..15
  const int scol = (lane & 3) * 4;  // 0,4,8,12

#pragma unroll
  for (int mi = 0; mi < 4; ++mi) {
    // write phase: scalar ds_write_b32, banks: l15 consecutive, quad 2-way
#pragma unroll
    for (int ni = 0; ni < 4; ++ni)
#pragma unroll
      for (int r = 0; r < 4; ++r)
        stage[(quad * 4 + r) * 68 + ni * 16 + l15] = acc[mi][ni][r] + bcol[ni];

    // read phase: wave-internal, DS in-order guarantees write->read
    const int rl = wm * 64 + mi * 16 + srow;
    const int row = row0 + rl;
    if (row < M) {
      const float* sp = stage + srow * 68;
      if (FUSED) {
        const bf16_t* vs = Vx + (size_t)sIdx[rl] * HDIM + n0 + wn * 64;
        const bf16_t* vd = Vx + (size_t)dIdx[rl] * HDIM + n0 + wn * 64;
        float* op = outF + (size_t)row * HDIM + n0 + wn * 64;
#pragma unroll
        for (int i = 0; i < 4; ++i) {
          const int c = i * 16 + scol;
          f32x4 a = *(const f32x4*)(sp + c);
          f32x4 sf = __builtin_convertvector(*(const bf16x4*)(vs + c), f32x4);
          f32x4 df = __builtin_convertvector(*(const bf16x4*)(vd + c), f32x4);
          *(f32x4*)(op + c) = a + sf + df;
        }
      } else {
        bf16_t* op = outB + (size_t)row * HDIM + n0 + wn * 64;
#pragma unroll
        for (int i = 0; i < 4; ++i) {
          const int c = i * 16 + scol;
          f32x4 a = *(const f32x4*)(sp + c);
          *(bf16x4*)(op + c) = __builtin_convertvector(a, bf16x4);
        }
      }
    }
  }
}

extern "C" void kernel_launch(void* const* d_in, const int* in_sizes, int n_in,
                              void* d_out, int out_size, void* d_ws,
                              size_t ws_size, hipStream_t stream) {
  const float* x = (const float*)d_in[0];     // (V, H) fp32
  const float* e = (const float*)d_in[1];     // (E, H) fp32
  const int* edge = (const int*)d_in[2];      // (2, E) int32: src then dst
  const float* Us_w = (const float*)d_in[3];  // (H, H) fp32
  const float* Us_b = (const float*)d_in[4];  // (H,) fp32
  const float* Vs_w = (const float*)d_in[5];  // (H, H) fp32
  const float* Vs_b = (const float*)d_in[6];  // (H,) fp32
  float* out = (float*)d_out;                 // (E, H) fp32

  bf16_t* us_w_b = (bf16_t*)d_ws;                         // 128 KB
  bf16_t* vs_w_b = (bf16_t*)((char*)d_ws + (128 << 10));  // 128 KB
  bf16_t* Vx = (bf16_t*)((char*)d_ws + (256 << 10));      // 5.12 MB

  dim3 blk(256, 1, 1);

  cvt_weights<<<dim3(64, 1, 1), blk, 0, stream>>>(Us_w, Vs_w, us_w_b, vs_w_b);

  dim3 g1((NV + 127) / 128, 2, 1);
  gemm<false><<<g1, blk, 0, stream>>>(x, vs_w_b, Vs_b, nullptr, nullptr,
                                      nullptr, nullptr, Vx, NV);

  dim3 g2((NE + 127) / 128, 2, 1);
  gemm<true><<<g2, blk, 0, stream>>>(e, us_w_b, Us_b, edge, edge + NE, Vx, out,
                                     nullptr, NE);
}